// Round 1
// 830.308 us; speedup vs baseline: 1.3792x; 1.3792x over previous
//
#include <hip/hip_runtime.h>
#include <math.h>

#define N_NODES 50000
#define N_EDGES 800000
#define N_ADJS  6
#define NHID    256
#define NB      196       // row buckets of 256 rows each: ceil(50000/256)
#define LN_EPS  1e-5f

typedef short bf16x8 __attribute__((ext_vector_type(8)));
typedef float f32x4  __attribute__((ext_vector_type(4)));
typedef _Float16 h4  __attribute__((ext_vector_type(4)));   // 8-byte fp16 quad

static __device__ __forceinline__ unsigned short f2bf(float f) {
    unsigned int x = __float_as_uint(f);
    unsigned int lsb = (x >> 16) & 1u;
    x += 0x7fffu + lsb;               // RTN-even
    return (unsigned short)(x >> 16);
}
static __device__ __forceinline__ float bf2f(unsigned short u) {
    return __uint_as_float(((unsigned int)u) << 16);
}

// -------------------- W -> bf16 hi/lo split --------------------
__global__ __launch_bounds__(256) void convert_w(const float* __restrict__ W,
                                                 unsigned short* __restrict__ Whi,
                                                 unsigned short* __restrict__ Wlo)
{
    const int i = blockIdx.x * 256 + threadIdx.x;   // 65536 total
    const float w = W[i];
    const unsigned short h = f2bf(w);
    Whi[i] = h;
    Wlo[i] = f2bf(w - bf2f(h));
}

// -------------------- h = x @ W^T + b via MFMA (bf16 split, fp32 acc) --------------------
// Block 256 = 4 waves; block computes 64 rows x 256 cols; wave w: rows w*16..w*16+15.
// Output h stored as fp16 (gather source format).
__global__ __launch_bounds__(256) void gemm_mfma(const float* __restrict__ x,
                                                 const unsigned short* __restrict__ Whi,
                                                 const unsigned short* __restrict__ Wlo,
                                                 const float* __restrict__ bias,
                                                 _Float16* __restrict__ h)
{
    const int tid = threadIdx.x;
    const int w = tid >> 6, l = tid & 63;
    const int m = l & 15, q = l >> 4;
    const int row0 = blockIdx.x * 64 + w * 16;
    const int arow = row0 + m;
    const int arow_c = (arow < N_NODES) ? arow : 0;

    f32x4 acc[16];
    #pragma unroll
    for (int nt = 0; nt < 16; ++nt) acc[nt] = (f32x4){0.f, 0.f, 0.f, 0.f};

    for (int kt = 0; kt < NHID; kt += 32) {
        const float* xp = x + (size_t)arow_c * NHID + kt + q * 8;
        const float4 xa = *(const float4*)xp;
        const float4 xb = *(const float4*)(xp + 4);
        const float xv[8] = {xa.x, xa.y, xa.z, xa.w, xb.x, xb.y, xb.z, xb.w};
        bf16x8 ah, al;
        #pragma unroll
        for (int j = 0; j < 8; ++j) {
            const unsigned short hh = f2bf(xv[j]);
            ah[j] = (short)hh;
            al[j] = (short)f2bf(xv[j] - bf2f(hh));
        }
        const int ko = kt + q * 8;
        #pragma unroll
        for (int nt = 0; nt < 16; ++nt) {
            const size_t off = (size_t)(nt * 16 + m) * NHID + ko;
            const bf16x8 bh = *(const bf16x8*)(Whi + off);
            const bf16x8 bl = *(const bf16x8*)(Wlo + off);
            acc[nt] = __builtin_amdgcn_mfma_f32_16x16x32_bf16(ah, bh, acc[nt], 0, 0, 0);
            acc[nt] = __builtin_amdgcn_mfma_f32_16x16x32_bf16(ah, bl, acc[nt], 0, 0, 0);
            acc[nt] = __builtin_amdgcn_mfma_f32_16x16x32_bf16(al, bh, acc[nt], 0, 0, 0);
        }
    }

    // C/D: col = lane&15, row = (lane>>4)*4 + reg
    #pragma unroll
    for (int nt = 0; nt < 16; ++nt) {
        const int col = nt * 16 + m;
        const float bv = bias[col];
        #pragma unroll
        for (int r = 0; r < 4; ++r) {
            const int grow = row0 + q * 4 + r;
            if (grow < N_NODES) h[(size_t)grow * NHID + col] = (_Float16)(acc[nt][r] + bv);
        }
    }
}

// -------------------- CSR build, pass A: bucket counts --------------------
__global__ __launch_bounds__(256) void bucket_count(const int* __restrict__ rows_all,
                                                    int* __restrict__ gcount)
{
    const int a = blockIdx.y;
    __shared__ int lcnt[NB];
    for (int i = threadIdx.x; i < NB; i += 256) lcnt[i] = 0;
    __syncthreads();
    const int e0 = blockIdx.x * 1024 + threadIdx.x;
    #pragma unroll
    for (int j = 0; j < 4; ++j) {
        const int e = e0 + j * 256;
        if (e < N_EDGES) {
            const int r = rows_all[(size_t)a * N_EDGES + e];
            atomicAdd(&lcnt[r >> 8], 1);
        }
    }
    __syncthreads();
    for (int i = threadIdx.x; i < NB; i += 256)
        if (lcnt[i]) atomicAdd(&gcount[a * NB + i], lcnt[i]);
}

// -------------------- CSR build: scan bucket counts (wave a scans adjacency a) --------------------
__global__ __launch_bounds__(384) void scan_buckets(const int* __restrict__ gcount,
                                                    int* __restrict__ bstart,
                                                    int* __restrict__ gcur,
                                                    int* __restrict__ row_start)
{
    const int lane = threadIdx.x & 63, a = threadIdx.x >> 6;
    if (a >= N_ADJS) return;
    int carry = 0;
    #pragma unroll
    for (int c = 0; c < 4; ++c) {
        const int i = c * 64 + lane;
        const int v = (i < NB) ? gcount[a * NB + i] : 0;
        int xs = v;
        #pragma unroll
        for (int d = 1; d < 64; d <<= 1) { const int t = __shfl_up(xs, d, 64); if (lane >= d) xs += t; }
        const int excl = carry + xs - v;
        if (i < NB) { bstart[a * (NB + 1) + i] = excl; gcur[a * NB + i] = excl; }
        carry += __shfl(xs, 63, 64);
    }
    if (lane == 0) {
        bstart[a * (NB + 1) + NB] = N_EDGES;
        row_start[(size_t)a * (N_NODES + 1) + N_NODES] = N_EDGES;
    }
}

// -------------------- CSR build, pass B: scatter into buckets (packed row|col, val) --------------------
__global__ __launch_bounds__(256) void bucket_scatter(const int* __restrict__ rows_all,
                                                      const int* __restrict__ cols_all,
                                                      const float* __restrict__ vals_all,
                                                      int* __restrict__ gcur,
                                                      int2* __restrict__ bucketed)
{
    const int a = blockIdx.y;
    __shared__ int lcnt[NB], lbase[NB];
    for (int i = threadIdx.x; i < NB; i += 256) lcnt[i] = 0;
    __syncthreads();
    int bq[4], sq[4]; int2 pq[4];
    const int e0 = blockIdx.x * 1024 + threadIdx.x;
    #pragma unroll
    for (int j = 0; j < 4; ++j) {
        const int e = e0 + j * 256;
        bq[j] = -1;
        if (e < N_EDGES) {
            const size_t idx = (size_t)a * N_EDGES + e;
            const int r = rows_all[idx];
            const int b = r >> 8;
            bq[j] = b;
            sq[j] = atomicAdd(&lcnt[b], 1);
            pq[j].x = (r << 16) | cols_all[idx];
            pq[j].y = __float_as_int(vals_all[idx]);
        }
    }
    __syncthreads();
    for (int i = threadIdx.x; i < NB; i += 256)
        lbase[i] = lcnt[i] ? atomicAdd(&gcur[a * NB + i], lcnt[i]) : 0;
    __syncthreads();
    int2* bk = bucketed + (size_t)a * N_EDGES;
    #pragma unroll
    for (int j = 0; j < 4; ++j)
        if (bq[j] >= 0) bk[lbase[bq[j]] + sq[j]] = pq[j];
}

// -------------------- CSR build, pass C: per-bucket row sort + row_start --------------------
__global__ __launch_bounds__(256) void build_csr(const int2* __restrict__ bucketed,
                                                 const int* __restrict__ bstart,
                                                 int* __restrict__ row_start,
                                                 int2* __restrict__ sorted_cv)
{
    const int a = blockIdx.y, b = blockIdx.x;
    const int s    = bstart[a * (NB + 1) + b];
    const int epnd = bstart[a * (NB + 1) + b + 1];
    __shared__ int cnt[256], cur[256];
    cnt[threadIdx.x] = 0;
    __syncthreads();
    const int2* bk = bucketed + (size_t)a * N_EDGES;
    for (int e = s + threadIdx.x; e < epnd; e += 256) {
        const unsigned p = (unsigned)bk[e].x;
        atomicAdd(&cnt[(p >> 16) & 255], 1);
    }
    __syncthreads();
    const int lane = threadIdx.x & 63, wid = threadIdx.x >> 6;
    if (wid == 0) {
        const int i0 = lane * 4;
        const int c0 = cnt[i0], c1 = cnt[i0 + 1], c2 = cnt[i0 + 2], c3 = cnt[i0 + 3];
        const int sum = c0 + c1 + c2 + c3;
        int xs = sum;
        #pragma unroll
        for (int d = 1; d < 64; d <<= 1) { const int t = __shfl_up(xs, d, 64); if (lane >= d) xs += t; }
        const int base = xs - sum;
        const int o0 = base, o1 = base + c0, o2 = o1 + c1, o3 = o2 + c2;
        cur[i0] = s + o0; cur[i0 + 1] = s + o1; cur[i0 + 2] = s + o2; cur[i0 + 3] = s + o3;
        int* rs = row_start + (size_t)a * (N_NODES + 1);
        const int gr = (b << 8) + i0;
        if (gr + 0 < N_NODES) rs[gr + 0] = s + o0;
        if (gr + 1 < N_NODES) rs[gr + 1] = s + o1;
        if (gr + 2 < N_NODES) rs[gr + 2] = s + o2;
        if (gr + 3 < N_NODES) rs[gr + 3] = s + o3;
    }
    __syncthreads();
    int2* sc = sorted_cv + (size_t)a * N_EDGES;
    for (int e = s + threadIdx.x; e < epnd; e += 256) {
        const int2 p = bk[e];
        const unsigned r = ((unsigned)p.x) >> 16;
        const int pos = atomicAdd(&cur[r & 255], 1);
        int2 cv; cv.x = p.x & 0xFFFF; cv.y = p.y;
        sc[pos] = cv;
    }
}

// -------------------- pull-mode SpMM over fp16 states, fp32 accumulate --------------------
static __device__ __forceinline__ void gacc(const _Float16* __restrict__ src,
                                            int col, float v, int lane, float4& acc)
{
    const h4 g = *(const h4*)(src + (size_t)col * NHID + lane * 4);
    acc.x += v * (float)g[0];
    acc.y += v * (float)g[1];
    acc.z += v * (float)g[2];
    acc.w += v * (float)g[3];
}

static __device__ __forceinline__ void pull_part(const int* __restrict__ row_start,
                                                 const int2* __restrict__ sorted_cv,
                                                 int a, const _Float16* __restrict__ src,
                                                 int row, int lane, float4& acc)
{
    const int2* cv = sorted_cv + (size_t)a * N_EDGES;
    const int* rs  = row_start + (size_t)a * (N_NODES + 1);
    const int s = rs[row], epnd = rs[row + 1];
    int e = s;
    for (; e + 3 < epnd; e += 4) {
        const int2 p0 = cv[e];
        const int2 p1 = cv[e + 1];
        const int2 p2 = cv[e + 2];
        const int2 p3 = cv[e + 3];
        gacc(src, p0.x, __int_as_float(p0.y), lane, acc);
        gacc(src, p1.x, __int_as_float(p1.y), lane, acc);
        gacc(src, p2.x, __int_as_float(p2.y), lane, acc);
        gacc(src, p3.x, __int_as_float(p3.y), lane, acc);
    }
    for (; e < epnd; ++e) {
        const int2 p0 = cv[e];
        gacc(src, p0.x, __int_as_float(p0.y), lane, acc);
    }
}

__global__ __launch_bounds__(256) void pull_spmm(
    const int* __restrict__ row_start, const int2* __restrict__ sorted_cv,
    const int* __restrict__ idx_a, int pos_a, const _Float16* __restrict__ src_a,
    const int* __restrict__ idx_b, int pos_b, const _Float16* __restrict__ src_b,
    const int* __restrict__ idx_c, int pos_c, const _Float16* __restrict__ src_c,
    _Float16* __restrict__ outh, float* __restrict__ outf,
    const float* __restrict__ gamma, const float* __restrict__ beta)
{
    const int row  = (blockIdx.x * 256 + threadIdx.x) >> 6;
    const int lane = threadIdx.x & 63;
    if (row >= N_NODES) return;
    float4 acc = {0.f, 0.f, 0.f, 0.f};
    pull_part(row_start, sorted_cv, idx_a[pos_a], src_a, row, lane, acc);
    if (src_b) pull_part(row_start, sorted_cv, idx_b[pos_b], src_b, row, lane, acc);
    if (src_c) pull_part(row_start, sorted_cv, idx_c[pos_c], src_c, row, lane, acc);

    if (gamma) {
        float sum = acc.x + acc.y + acc.z + acc.w;
        float sq  = acc.x * acc.x + acc.y * acc.y + acc.z * acc.z + acc.w * acc.w;
        #pragma unroll
        for (int off = 1; off < 64; off <<= 1) {
            sum += __shfl_xor(sum, off, 64);
            sq  += __shfl_xor(sq,  off, 64);
        }
        const float mu   = sum * (1.f / NHID);
        const float var  = sq * (1.f / NHID) - mu * mu;
        const float rstd = rsqrtf(var + LN_EPS);
        const float4 g4 = *(const float4*)(gamma + lane * 4);
        const float4 b4 = *(const float4*)(beta + lane * 4);
        const float in4[4] = {acc.x, acc.y, acc.z, acc.w};
        const float g[4]  = {g4.x, g4.y, g4.z, g4.w};
        const float bb[4] = {b4.x, b4.y, b4.z, b4.w};
        float4 o; float* op = (float*)&o;
        #pragma unroll
        for (int j = 0; j < 4; ++j) {
            const float y = (in4[j] - mu) * rstd * g[j] + bb[j];
            op[j] = 0.5f * y * (1.f + erff(y * 0.70710678118654752f));
        }
        *(float4*)(outf + (size_t)row * NHID + lane * 4) = o;
    } else {
        h4 o;
        o[0] = (_Float16)acc.x; o[1] = (_Float16)acc.y;
        o[2] = (_Float16)acc.z; o[3] = (_Float16)acc.w;
        *(h4*)(outh + (size_t)row * NHID + lane * 4) = o;
    }
}

extern "C" void kernel_launch(void* const* d_in, const int* in_sizes, int n_in,
                              void* d_out, int out_size, void* d_ws, size_t ws_size,
                              hipStream_t stream)
{
    (void)in_sizes; (void)n_in; (void)out_size; (void)ws_size;
    const float* x        = (const float*)d_in[0];
    const int* adj_rows   = (const int*)d_in[1];
    const int* adj_cols   = (const int*)d_in[2];
    const float* vals     = (const float*)d_in[3];
    const int* idx_seq    = (const int*)d_in[4];
    const int* idx_res    = (const int*)d_in[5];
    const float* W        = (const float*)d_in[6];
    const float* bias     = (const float*)d_in[7];
    const float* gam      = (const float*)d_in[8];
    const float* bet      = (const float*)d_in[9];

    const size_t S = (size_t)N_NODES * NHID;
    _Float16* s0 = (_Float16*)d_ws;            // 25.6 MB each
    _Float16* s1 = s0 + S;
    _Float16* s2 = s1 + S;
    int2*  sorted_cv      = (int2*)(s2 + S);                                  // 38.4 MB
    int*   row_start      = (int*)(sorted_cv + (size_t)N_ADJS * N_EDGES);     // 1.2 MB
    unsigned short* Whi   = (unsigned short*)(row_start + (size_t)N_ADJS * (N_NODES + 1)); // 128 KB
    unsigned short* Wlo   = Whi + NHID * NHID;                                // 128 KB
    int*   gcount         = (int*)(Wlo + NHID * NHID);
    int*   bstart         = gcount + N_ADJS * NB;
    int*   gcur           = bstart + N_ADJS * (NB + 1);
    // bucketed aliases s1+s2 (51.2 MB fp16 combined >= 38.4 MB needed):
    // dead once build_csr finishes, before pull1 writes s1.
    int2*  bucketed       = (int2*)s1;

    hipMemsetAsync(gcount, 0, (size_t)N_ADJS * NB * sizeof(int), stream);

    convert_w<<<dim3(NHID * NHID / 256), dim3(256), 0, stream>>>(W, Whi, Wlo);
    gemm_mfma<<<dim3((N_NODES + 63) / 64), dim3(256), 0, stream>>>(x, Whi, Wlo, bias, s0);

    const int eblocks = (N_EDGES + 1023) / 1024;
    bucket_count<<<dim3(eblocks, N_ADJS), dim3(256), 0, stream>>>(adj_rows, gcount);
    scan_buckets<<<dim3(1), dim3(384), 0, stream>>>(gcount, bstart, gcur, row_start);
    bucket_scatter<<<dim3(eblocks, N_ADJS), dim3(256), 0, stream>>>(adj_rows, adj_cols, vals, gcur, bucketed);
    build_csr<<<dim3(NB, N_ADJS), dim3(256), 0, stream>>>(bucketed, bstart, row_start, sorted_cv);

    const dim3 pgrid(N_NODES * 64 / 256);
    pull_spmm<<<pgrid, dim3(256), 0, stream>>>(row_start, sorted_cv,
        idx_seq, 0, s0,  nullptr, 0, nullptr,  nullptr, 0, nullptr,
        s1, nullptr, nullptr, nullptr);
    pull_spmm<<<pgrid, dim3(256), 0, stream>>>(row_start, sorted_cv,
        idx_seq, 1, s1,  idx_res, 0, s0,  nullptr, 0, nullptr,
        s2, nullptr, nullptr, nullptr);
    pull_spmm<<<pgrid, dim3(256), 0, stream>>>(row_start, sorted_cv,
        idx_seq, 2, s2,  idx_res, 1, s0,  idx_res, 2, s1,
        nullptr, (float*)d_out, gam, bet);
}

// Round 3
// 758.181 us; speedup vs baseline: 1.5104x; 1.0951x over previous
//
#include <hip/hip_runtime.h>
#include <math.h>

#define N_NODES 50000
#define N_EDGES 800000
#define N_ADJS  6
#define NHID    256
#define BSHIFT  7         // 128-row buckets
#define NB      391       // ceil(50000/128)
#define BCAP    3072      // LDS bucket capacity (mean ~2046, max ~2300)
#define LN_EPS  1e-5f

typedef short bf16x8 __attribute__((ext_vector_type(8)));
typedef float f32x4  __attribute__((ext_vector_type(4)));
typedef _Float16 h4  __attribute__((ext_vector_type(4)));   // 8-byte fp16 quad

static __device__ __forceinline__ unsigned short f2bf(float f) {
    unsigned int x = __float_as_uint(f);
    unsigned int lsb = (x >> 16) & 1u;
    x += 0x7fffu + lsb;               // RTN-even
    return (unsigned short)(x >> 16);
}
static __device__ __forceinline__ float bf2f(unsigned short u) {
    return __uint_as_float(((unsigned int)u) << 16);
}

// -------------------- W -> bf16 hi/lo split --------------------
__global__ __launch_bounds__(256) void convert_w(const float* __restrict__ W,
                                                 unsigned short* __restrict__ Whi,
                                                 unsigned short* __restrict__ Wlo)
{
    const int i = blockIdx.x * 256 + threadIdx.x;   // 65536 total
    const float w = W[i];
    const unsigned short h = f2bf(w);
    Whi[i] = h;
    Wlo[i] = f2bf(w - bf2f(h));
}

// -------------------- h = x @ W^T + b via MFMA (bf16 split, fp32 acc) --------------------
__global__ __launch_bounds__(256) void gemm_mfma(const float* __restrict__ x,
                                                 const unsigned short* __restrict__ Whi,
                                                 const unsigned short* __restrict__ Wlo,
                                                 const float* __restrict__ bias,
                                                 _Float16* __restrict__ h)
{
    const int tid = threadIdx.x;
    const int w = tid >> 6, l = tid & 63;
    const int m = l & 15, q = l >> 4;
    const int row0 = blockIdx.x * 64 + w * 16;
    const int arow = row0 + m;
    const int arow_c = (arow < N_NODES) ? arow : 0;

    f32x4 acc[16];
    #pragma unroll
    for (int nt = 0; nt < 16; ++nt) acc[nt] = (f32x4){0.f, 0.f, 0.f, 0.f};

    for (int kt = 0; kt < NHID; kt += 32) {
        const float* xp = x + (size_t)arow_c * NHID + kt + q * 8;
        const float4 xa = *(const float4*)xp;
        const float4 xb = *(const float4*)(xp + 4);
        const float xv[8] = {xa.x, xa.y, xa.z, xa.w, xb.x, xb.y, xb.z, xb.w};
        bf16x8 ah, al;
        #pragma unroll
        for (int j = 0; j < 8; ++j) {
            const unsigned short hh = f2bf(xv[j]);
            ah[j] = (short)hh;
            al[j] = (short)f2bf(xv[j] - bf2f(hh));
        }
        const int ko = kt + q * 8;
        #pragma unroll
        for (int nt = 0; nt < 16; ++nt) {
            const size_t off = (size_t)(nt * 16 + m) * NHID + ko;
            const bf16x8 bh = *(const bf16x8*)(Whi + off);
            const bf16x8 bl = *(const bf16x8*)(Wlo + off);
            acc[nt] = __builtin_amdgcn_mfma_f32_16x16x32_bf16(ah, bh, acc[nt], 0, 0, 0);
            acc[nt] = __builtin_amdgcn_mfma_f32_16x16x32_bf16(ah, bl, acc[nt], 0, 0, 0);
            acc[nt] = __builtin_amdgcn_mfma_f32_16x16x32_bf16(al, bh, acc[nt], 0, 0, 0);
        }
    }

    // C/D: col = lane&15, row = (lane>>4)*4 + reg
    #pragma unroll
    for (int nt = 0; nt < 16; ++nt) {
        const int col = nt * 16 + m;
        const float bv = bias[col];
        #pragma unroll
        for (int r = 0; r < 4; ++r) {
            const int grow = row0 + q * 4 + r;
            if (grow < N_NODES) h[(size_t)grow * NHID + col] = (_Float16)(acc[nt][r] + bv);
        }
    }
}

// -------------------- CSR build, pass A: bucket counts (2048 edges/block) --------------------
__global__ __launch_bounds__(256) void bucket_count(const int* __restrict__ rows_all,
                                                    int* __restrict__ gcount)
{
    const int a = blockIdx.y;
    __shared__ int lcnt[NB];
    for (int i = threadIdx.x; i < NB; i += 256) lcnt[i] = 0;
    __syncthreads();
    const int e0 = blockIdx.x * 2048 + threadIdx.x;
    #pragma unroll
    for (int j = 0; j < 8; ++j) {
        const int e = e0 + j * 256;
        if (e < N_EDGES) {
            const int r = rows_all[(size_t)a * N_EDGES + e];
            atomicAdd(&lcnt[r >> BSHIFT], 1);
        }
    }
    __syncthreads();
    for (int i = threadIdx.x; i < NB; i += 256)
        if (lcnt[i]) atomicAdd(&gcount[a * NB + i], lcnt[i]);
}

// -------------------- CSR build: scan bucket counts (wave a scans adjacency a) --------------------
__global__ __launch_bounds__(384) void scan_buckets(const int* __restrict__ gcount,
                                                    int* __restrict__ bstart,
                                                    int* __restrict__ gcur,
                                                    int* __restrict__ row_start)
{
    const int lane = threadIdx.x & 63, a = threadIdx.x >> 6;
    if (a >= N_ADJS) return;
    int carry = 0;
    #pragma unroll
    for (int c = 0; c < 7; ++c) {
        const int i = c * 64 + lane;
        const int v = (i < NB) ? gcount[a * NB + i] : 0;
        int xs = v;
        #pragma unroll
        for (int d = 1; d < 64; d <<= 1) { const int t = __shfl_up(xs, d, 64); if (lane >= d) xs += t; }
        const int excl = carry + xs - v;
        if (i < NB) { bstart[a * (NB + 1) + i] = excl; gcur[a * NB + i] = excl; }
        carry += __shfl(xs, 63, 64);
    }
    if (lane == 0) {
        bstart[a * (NB + 1) + NB] = N_EDGES;
        row_start[(size_t)a * (N_NODES + 1) + N_NODES] = N_EDGES;
    }
}

// -------------------- CSR build, pass B: scatter into buckets (2048 edges/block) --------------------
__global__ __launch_bounds__(256) void bucket_scatter(const int* __restrict__ rows_all,
                                                      const int* __restrict__ cols_all,
                                                      const float* __restrict__ vals_all,
                                                      int* __restrict__ gcur,
                                                      int2* __restrict__ bucketed)
{
    const int a = blockIdx.y;
    __shared__ int lcnt[NB], lbase[NB];
    for (int i = threadIdx.x; i < NB; i += 256) lcnt[i] = 0;
    __syncthreads();
    int bq[8], sq[8]; int2 pq[8];
    const int e0 = blockIdx.x * 2048 + threadIdx.x;
    #pragma unroll
    for (int j = 0; j < 8; ++j) {
        const int e = e0 + j * 256;
        bq[j] = -1;
        if (e < N_EDGES) {
            const size_t idx = (size_t)a * N_EDGES + e;
            const int r = rows_all[idx];
            const int b = r >> BSHIFT;
            bq[j] = b;
            sq[j] = atomicAdd(&lcnt[b], 1);
            pq[j].x = (r << 16) | cols_all[idx];
            pq[j].y = __float_as_int(vals_all[idx]);
        }
    }
    __syncthreads();
    for (int i = threadIdx.x; i < NB; i += 256)
        lbase[i] = lcnt[i] ? atomicAdd(&gcur[a * NB + i], lcnt[i]) : 0;
    __syncthreads();
    int2* bk = bucketed + (size_t)a * N_EDGES;
    #pragma unroll
    for (int j = 0; j < 8; ++j)
        if (bq[j] >= 0) bk[lbase[bq[j]] + sq[j]] = pq[j];
}

// -------------------- CSR build, pass C: LDS-staged per-bucket row sort --------------------
// Bucket (~2K edges) staged in LDS, histogrammed, rank-scattered in LDS,
// written out coalesced. Fallback to global scatter if bucket > BCAP.
__global__ __launch_bounds__(256) void build_csr(const int2* __restrict__ bucketed,
                                                 const int* __restrict__ bstart,
                                                 int* __restrict__ row_start,
                                                 int2* __restrict__ sorted_cv)
{
    const int a = blockIdx.y, b = blockIdx.x;
    const int s    = bstart[a * (NB + 1) + b];
    const int epnd = bstart[a * (NB + 1) + b + 1];
    const int n = epnd - s;
    __shared__ int cnt[128], cur[128];
    __shared__ int2 buf[BCAP];    // 24 KB
    __shared__ int2 buf2[BCAP];   // 24 KB
    if (threadIdx.x < 128) cnt[threadIdx.x] = 0;
    __syncthreads();
    const int2* bk = bucketed + (size_t)a * N_EDGES;
    const bool fits = (n <= BCAP);
    for (int i = threadIdx.x; i < n; i += 256) {
        const int2 p = bk[s + i];
        if (fits) buf[i] = p;
        atomicAdd(&cnt[(p.x >> 16) & 127], 1);
    }
    __syncthreads();
    const int lane = threadIdx.x & 63, wid = threadIdx.x >> 6;
    if (wid == 0) {
        const int i0 = lane * 2;
        const int c0 = cnt[i0], c1 = cnt[i0 + 1];
        const int sum = c0 + c1;
        int xs = sum;
        #pragma unroll
        for (int d = 1; d < 64; d <<= 1) { const int t = __shfl_up(xs, d, 64); if (lane >= d) xs += t; }
        const int base = xs - sum;        // exclusive, local to bucket
        const int o0 = base, o1 = base + c0;
        cur[i0] = o0; cur[i0 + 1] = o1;
        int* rs = row_start + (size_t)a * (N_NODES + 1);
        const int gr = (b << BSHIFT) + i0;
        if (gr + 0 < N_NODES) rs[gr + 0] = s + o0;
        if (gr + 1 < N_NODES) rs[gr + 1] = s + o1;
    }
    __syncthreads();
    int2* sc = sorted_cv + (size_t)a * N_EDGES;
    if (fits) {
        for (int i = threadIdx.x; i < n; i += 256) {
            const int2 p = buf[i];
            const int pos = atomicAdd(&cur[(p.x >> 16) & 127], 1);
            int2 cv; cv.x = p.x & 0xFFFF; cv.y = p.y;
            buf2[pos] = cv;
        }
        __syncthreads();
        for (int i = threadIdx.x; i < n; i += 256)
            sc[s + i] = buf2[i];                    // coalesced streaming write
    } else {
        for (int e = s + threadIdx.x; e < epnd; e += 256) {
            const int2 p = bk[e];
            const int pos = atomicAdd(&cur[(p.x >> 16) & 127], 1);
            int2 cv; cv.x = p.x & 0xFFFF; cv.y = p.y;
            sc[s + pos] = cv;
        }
    }
}

// -------------------- pull-mode SpMM over fp16 states, fp32 accumulate --------------------
static __device__ __forceinline__ void gacc(const _Float16* __restrict__ src,
                                            int col, float v, int lane, float4& acc)
{
    const h4 g = *(const h4*)(src + (size_t)col * NHID + lane * 4);
    acc.x += v * (float)g[0];
    acc.y += v * (float)g[1];
    acc.z += v * (float)g[2];
    acc.w += v * (float)g[3];
}

static __device__ __forceinline__ void pull_part(const int* __restrict__ row_start,
                                                 const int2* __restrict__ sorted_cv,
                                                 int a, const _Float16* __restrict__ src,
                                                 int row, int lane, float4& acc)
{
    const int2* cv = sorted_cv + (size_t)a * N_EDGES;
    const int* rs  = row_start + (size_t)a * (N_NODES + 1);
    const int s = rs[row], epnd = rs[row + 1];
    int e = s;
    for (; e + 3 < epnd; e += 4) {
        const int2 p0 = cv[e];
        const int2 p1 = cv[e + 1];
        const int2 p2 = cv[e + 2];
        const int2 p3 = cv[e + 3];
        gacc(src, p0.x, __int_as_float(p0.y), lane, acc);
        gacc(src, p1.x, __int_as_float(p1.y), lane, acc);
        gacc(src, p2.x, __int_as_float(p2.y), lane, acc);
        gacc(src, p3.x, __int_as_float(p3.y), lane, acc);
    }
    for (; e < epnd; ++e) {
        const int2 p0 = cv[e];
        gacc(src, p0.x, __int_as_float(p0.y), lane, acc);
    }
}

template<int PARTS, bool LN>
__global__ __launch_bounds__(256) void pull_spmm(
    const int* __restrict__ row_start, const int2* __restrict__ sorted_cv,
    const int* __restrict__ idx_a, int pos_a, const _Float16* __restrict__ src_a,
    const int* __restrict__ idx_b, int pos_b, const _Float16* __restrict__ src_b,
    const int* __restrict__ idx_c, int pos_c, const _Float16* __restrict__ src_c,
    _Float16* __restrict__ outh, float* __restrict__ outf,
    const float* __restrict__ gamma, const float* __restrict__ beta)
{
    const int row  = (blockIdx.x * 256 + threadIdx.x) >> 6;
    const int lane = threadIdx.x & 63;
    if (row >= N_NODES) return;
    float4 acc = {0.f, 0.f, 0.f, 0.f};
    pull_part(row_start, sorted_cv, idx_a[pos_a], src_a, row, lane, acc);
    if constexpr (PARTS >= 2) pull_part(row_start, sorted_cv, idx_b[pos_b], src_b, row, lane, acc);
    if constexpr (PARTS >= 3) pull_part(row_start, sorted_cv, idx_c[pos_c], src_c, row, lane, acc);

    if constexpr (LN) {
        float sum = acc.x + acc.y + acc.z + acc.w;
        float sq  = acc.x * acc.x + acc.y * acc.y + acc.z * acc.z + acc.w * acc.w;
        #pragma unroll
        for (int off = 1; off < 64; off <<= 1) {
            sum += __shfl_xor(sum, off, 64);
            sq  += __shfl_xor(sq,  off, 64);
        }
        const float mu   = sum * (1.f / NHID);
        const float var  = sq * (1.f / NHID) - mu * mu;
        const float rstd = rsqrtf(var + LN_EPS);
        const float4 g4 = *(const float4*)(gamma + lane * 4);
        const float4 b4 = *(const float4*)(beta + lane * 4);
        const float in4[4] = {acc.x, acc.y, acc.z, acc.w};
        const float g[4]  = {g4.x, g4.y, g4.z, g4.w};
        const float bb[4] = {b4.x, b4.y, b4.z, b4.w};
        float4 o; float* op = (float*)&o;
        #pragma unroll
        for (int j = 0; j < 4; ++j) {
            const float y = (in4[j] - mu) * rstd * g[j] + bb[j];
            op[j] = 0.5f * y * (1.f + erff(y * 0.70710678118654752f));
        }
        *(float4*)(outf + (size_t)row * NHID + lane * 4) = o;
    } else {
        h4 o;
        o[0] = (_Float16)acc.x; o[1] = (_Float16)acc.y;
        o[2] = (_Float16)acc.z; o[3] = (_Float16)acc.w;
        *(h4*)(outh + (size_t)row * NHID + lane * 4) = o;
    }
}

extern "C" void kernel_launch(void* const* d_in, const int* in_sizes, int n_in,
                              void* d_out, int out_size, void* d_ws, size_t ws_size,
                              hipStream_t stream)
{
    (void)in_sizes; (void)n_in; (void)out_size; (void)ws_size;
    const float* x        = (const float*)d_in[0];
    const int* adj_rows   = (const int*)d_in[1];
    const int* adj_cols   = (const int*)d_in[2];
    const float* vals     = (const float*)d_in[3];
    const int* idx_seq    = (const int*)d_in[4];
    const int* idx_res    = (const int*)d_in[5];
    const float* W        = (const float*)d_in[6];
    const float* bias     = (const float*)d_in[7];
    const float* gam      = (const float*)d_in[8];
    const float* bet      = (const float*)d_in[9];

    const size_t S = (size_t)N_NODES * NHID;
    _Float16* s0 = (_Float16*)d_ws;            // 25.6 MB each
    _Float16* s1 = s0 + S;
    _Float16* s2 = s1 + S;
    int2*  sorted_cv      = (int2*)(s2 + S);                                  // 38.4 MB
    int*   row_start      = (int*)(sorted_cv + (size_t)N_ADJS * N_EDGES);     // 1.2 MB
    unsigned short* Whi   = (unsigned short*)(row_start + (size_t)N_ADJS * (N_NODES + 1)); // 128 KB
    unsigned short* Wlo   = Whi + NHID * NHID;                                // 128 KB
    int*   gcount         = (int*)(Wlo + NHID * NHID);
    int*   bstart         = gcount + N_ADJS * NB;
    int*   gcur           = bstart + N_ADJS * (NB + 1);
    // bucketed aliases s1+s2 (51.2 MB fp16 combined >= 38.4 MB needed):
    // dead once build_csr finishes, before pull1 writes s1.
    int2*  bucketed       = (int2*)s1;

    hipMemsetAsync(gcount, 0, (size_t)N_ADJS * NB * sizeof(int), stream);

    convert_w<<<dim3(NHID * NHID / 256), dim3(256), 0, stream>>>(W, Whi, Wlo);
    gemm_mfma<<<dim3((N_NODES + 63) / 64), dim3(256), 0, stream>>>(x, Whi, Wlo, bias, s0);

    const int eblocks = (N_EDGES + 2047) / 2048;
    bucket_count<<<dim3(eblocks, N_ADJS), dim3(256), 0, stream>>>(adj_rows, gcount);
    scan_buckets<<<dim3(1), dim3(384), 0, stream>>>(gcount, bstart, gcur, row_start);
    bucket_scatter<<<dim3(eblocks, N_ADJS), dim3(256), 0, stream>>>(adj_rows, adj_cols, vals, gcur, bucketed);
    build_csr<<<dim3(NB, N_ADJS), dim3(256), 0, stream>>>(bucketed, bstart, row_start, sorted_cv);

    const dim3 pgrid(N_NODES * 64 / 256);
    pull_spmm<1, false><<<pgrid, dim3(256), 0, stream>>>(row_start, sorted_cv,
        idx_seq, 0, s0,  nullptr, 0, nullptr,  nullptr, 0, nullptr,
        s1, nullptr, nullptr, nullptr);
    pull_spmm<2, false><<<pgrid, dim3(256), 0, stream>>>(row_start, sorted_cv,
        idx_seq, 1, s1,  idx_res, 0, s0,  nullptr, 0, nullptr,
        s2, nullptr, nullptr, nullptr);
    pull_spmm<3, true><<<pgrid, dim3(256), 0, stream>>>(row_start, sorted_cv,
        idx_seq, 2, s2,  idx_res, 1, s0,  idx_res, 2, s1,
        nullptr, (float*)d_out, gam, bet);
}

// Round 4
// 745.480 us; speedup vs baseline: 1.5361x; 1.0170x over previous
//
#include <hip/hip_runtime.h>
#include <math.h>

#define N_NODES 50000
#define N_EDGES 800000
#define N_ADJS  6
#define NHID    256
#define BSHIFT  7         // 128-row buckets
#define NB      391       // ceil(50000/128)
#define BCAP    3072      // LDS bucket capacity (mean ~2046, max ~2300)
#define LN_EPS  1e-5f

typedef short bf16x8 __attribute__((ext_vector_type(8)));
typedef float f32x4  __attribute__((ext_vector_type(4)));
typedef _Float16 h4  __attribute__((ext_vector_type(4)));   // 8-byte fp16 quad
typedef int i32x2    __attribute__((ext_vector_type(2)));

static __device__ __forceinline__ unsigned short f2bf(float f) {
    unsigned int x = __float_as_uint(f);
    unsigned int lsb = (x >> 16) & 1u;
    x += 0x7fffu + lsb;               // RTN-even
    return (unsigned short)(x >> 16);
}
static __device__ __forceinline__ float bf2f(unsigned short u) {
    return __uint_as_float(((unsigned int)u) << 16);
}

// -------------------- W -> bf16 hi/lo split --------------------
__global__ __launch_bounds__(256) void convert_w(const float* __restrict__ W,
                                                 unsigned short* __restrict__ Whi,
                                                 unsigned short* __restrict__ Wlo)
{
    const int i = blockIdx.x * 256 + threadIdx.x;   // 65536 total
    const float w = W[i];
    const unsigned short h = f2bf(w);
    Whi[i] = h;
    Wlo[i] = f2bf(w - bf2f(h));
}

// -------------------- h = x @ W^T + b via MFMA (bf16 split, fp32 acc) --------------------
__global__ __launch_bounds__(256) void gemm_mfma(const float* __restrict__ x,
                                                 const unsigned short* __restrict__ Whi,
                                                 const unsigned short* __restrict__ Wlo,
                                                 const float* __restrict__ bias,
                                                 _Float16* __restrict__ h)
{
    const int tid = threadIdx.x;
    const int w = tid >> 6, l = tid & 63;
    const int m = l & 15, q = l >> 4;
    const int row0 = blockIdx.x * 64 + w * 16;
    const int arow = row0 + m;
    const int arow_c = (arow < N_NODES) ? arow : 0;

    f32x4 acc[16];
    #pragma unroll
    for (int nt = 0; nt < 16; ++nt) acc[nt] = (f32x4){0.f, 0.f, 0.f, 0.f};

    for (int kt = 0; kt < NHID; kt += 32) {
        const float* xp = x + (size_t)arow_c * NHID + kt + q * 8;
        const float4 xa = *(const float4*)xp;
        const float4 xb = *(const float4*)(xp + 4);
        const float xv[8] = {xa.x, xa.y, xa.z, xa.w, xb.x, xb.y, xb.z, xb.w};
        bf16x8 ah, al;
        #pragma unroll
        for (int j = 0; j < 8; ++j) {
            const unsigned short hh = f2bf(xv[j]);
            ah[j] = (short)hh;
            al[j] = (short)f2bf(xv[j] - bf2f(hh));
        }
        const int ko = kt + q * 8;
        #pragma unroll
        for (int nt = 0; nt < 16; ++nt) {
            const size_t off = (size_t)(nt * 16 + m) * NHID + ko;
            const bf16x8 bh = *(const bf16x8*)(Whi + off);
            const bf16x8 bl = *(const bf16x8*)(Wlo + off);
            acc[nt] = __builtin_amdgcn_mfma_f32_16x16x32_bf16(ah, bh, acc[nt], 0, 0, 0);
            acc[nt] = __builtin_amdgcn_mfma_f32_16x16x32_bf16(ah, bl, acc[nt], 0, 0, 0);
            acc[nt] = __builtin_amdgcn_mfma_f32_16x16x32_bf16(al, bh, acc[nt], 0, 0, 0);
        }
    }

    // C/D: col = lane&15, row = (lane>>4)*4 + reg
    #pragma unroll
    for (int nt = 0; nt < 16; ++nt) {
        const int col = nt * 16 + m;
        const float bv = bias[col];
        #pragma unroll
        for (int r = 0; r < 4; ++r) {
            const int grow = row0 + q * 4 + r;
            if (grow < N_NODES) h[(size_t)grow * NHID + col] = (_Float16)(acc[nt][r] + bv);
        }
    }
}

// -------------------- CSR build, pass A: bucket counts (4096 edges/block) --------------------
__global__ __launch_bounds__(256) void bucket_count(const int* __restrict__ rows_all,
                                                    int* __restrict__ gcount)
{
    const int a = blockIdx.y;
    __shared__ int lcnt[NB];
    for (int i = threadIdx.x; i < NB; i += 256) lcnt[i] = 0;
    __syncthreads();
    const int e0 = blockIdx.x * 4096 + threadIdx.x;
    #pragma unroll
    for (int j = 0; j < 16; ++j) {
        const int e = e0 + j * 256;
        if (e < N_EDGES) {
            const int r = rows_all[(size_t)a * N_EDGES + e];
            atomicAdd(&lcnt[r >> BSHIFT], 1);
        }
    }
    __syncthreads();
    for (int i = threadIdx.x; i < NB; i += 256)
        if (lcnt[i]) atomicAdd(&gcount[a * NB + i], lcnt[i]);
}

// -------------------- CSR build: scan bucket counts (wave a scans adjacency a) --------------------
__global__ __launch_bounds__(384) void scan_buckets(const int* __restrict__ gcount,
                                                    int* __restrict__ bstart,
                                                    int* __restrict__ gcur,
                                                    int* __restrict__ row_start)
{
    const int lane = threadIdx.x & 63, a = threadIdx.x >> 6;
    if (a >= N_ADJS) return;
    int carry = 0;
    #pragma unroll
    for (int c = 0; c < 7; ++c) {
        const int i = c * 64 + lane;
        const int v = (i < NB) ? gcount[a * NB + i] : 0;
        int xs = v;
        #pragma unroll
        for (int d = 1; d < 64; d <<= 1) { const int t = __shfl_up(xs, d, 64); if (lane >= d) xs += t; }
        const int excl = carry + xs - v;
        if (i < NB) { bstart[a * (NB + 1) + i] = excl; gcur[a * NB + i] = excl; }
        carry += __shfl(xs, 63, 64);
    }
    if (lane == 0) {
        bstart[a * (NB + 1) + NB] = N_EDGES;
        row_start[(size_t)a * (N_NODES + 1) + N_NODES] = N_EDGES;
    }
}

// -------------------- CSR build, pass B: scatter into buckets (4096 edges/block) --------------------
__global__ __launch_bounds__(256) void bucket_scatter(const int* __restrict__ rows_all,
                                                      const int* __restrict__ cols_all,
                                                      const float* __restrict__ vals_all,
                                                      int* __restrict__ gcur,
                                                      int2* __restrict__ bucketed)
{
    const int a = blockIdx.y;
    __shared__ int lcnt[NB], lbase[NB];
    for (int i = threadIdx.x; i < NB; i += 256) lcnt[i] = 0;
    __syncthreads();
    int bq[16], sq[16]; int2 pq[16];
    const int e0 = blockIdx.x * 4096 + threadIdx.x;
    #pragma unroll
    for (int j = 0; j < 16; ++j) {
        const int e = e0 + j * 256;
        bq[j] = -1;
        if (e < N_EDGES) {
            const size_t idx = (size_t)a * N_EDGES + e;
            const int r = rows_all[idx];
            const int b = r >> BSHIFT;
            bq[j] = b;
            sq[j] = atomicAdd(&lcnt[b], 1);
            pq[j].x = (r << 16) | cols_all[idx];
            pq[j].y = __float_as_int(vals_all[idx]);
        }
    }
    __syncthreads();
    for (int i = threadIdx.x; i < NB; i += 256)
        lbase[i] = lcnt[i] ? atomicAdd(&gcur[a * NB + i], lcnt[i]) : 0;
    __syncthreads();
    int2* bk = bucketed + (size_t)a * N_EDGES;
    #pragma unroll
    for (int j = 0; j < 16; ++j)
        if (bq[j] >= 0) bk[lbase[bq[j]] + sq[j]] = pq[j];
}

// -------------------- CSR build, pass C: LDS-staged per-bucket row sort --------------------
__global__ __launch_bounds__(256) void build_csr(const int2* __restrict__ bucketed,
                                                 const int* __restrict__ bstart,
                                                 int* __restrict__ row_start,
                                                 int2* __restrict__ sorted_cv)
{
    const int a = blockIdx.y, b = blockIdx.x;
    const int s    = bstart[a * (NB + 1) + b];
    const int epnd = bstart[a * (NB + 1) + b + 1];
    const int n = epnd - s;
    __shared__ int cnt[128], cur[128];
    __shared__ int2 buf[BCAP];    // 24 KB
    __shared__ int2 buf2[BCAP];   // 24 KB
    if (threadIdx.x < 128) cnt[threadIdx.x] = 0;
    __syncthreads();
    const int2* bk = bucketed + (size_t)a * N_EDGES;
    const bool fits = (n <= BCAP);
    for (int i = threadIdx.x; i < n; i += 256) {
        const int2 p = bk[s + i];
        if (fits) buf[i] = p;
        atomicAdd(&cnt[(p.x >> 16) & 127], 1);
    }
    __syncthreads();
    const int lane = threadIdx.x & 63, wid = threadIdx.x >> 6;
    if (wid == 0) {
        const int i0 = lane * 2;
        const int c0 = cnt[i0], c1 = cnt[i0 + 1];
        const int sum = c0 + c1;
        int xs = sum;
        #pragma unroll
        for (int d = 1; d < 64; d <<= 1) { const int t = __shfl_up(xs, d, 64); if (lane >= d) xs += t; }
        const int base = xs - sum;        // exclusive, local to bucket
        const int o0 = base, o1 = base + c0;
        cur[i0] = o0; cur[i0 + 1] = o1;
        int* rs = row_start + (size_t)a * (N_NODES + 1);
        const int gr = (b << BSHIFT) + i0;
        if (gr + 0 < N_NODES) rs[gr + 0] = s + o0;
        if (gr + 1 < N_NODES) rs[gr + 1] = s + o1;
    }
    __syncthreads();
    int2* sc = sorted_cv + (size_t)a * N_EDGES;
    if (fits) {
        for (int i = threadIdx.x; i < n; i += 256) {
            const int2 p = buf[i];
            const int pos = atomicAdd(&cur[(p.x >> 16) & 127], 1);
            int2 cv; cv.x = p.x & 0xFFFF; cv.y = p.y;
            buf2[pos] = cv;
        }
        __syncthreads();
        for (int i = threadIdx.x; i < n; i += 256)
            sc[s + i] = buf2[i];                    // coalesced streaming write
    } else {
        for (int e = s + threadIdx.x; e < epnd; e += 256) {
            const int2 p = bk[e];
            const int pos = atomicAdd(&cur[(p.x >> 16) & 127], 1);
            int2 cv; cv.x = p.x & 0xFFFF; cv.y = p.y;
            sc[s + pos] = cv;
        }
    }
}

// -------------------- pull-mode SpMM over fp16 states, fp32 accumulate --------------------
// MLP-deepened: batch 8 cv loads (nontemporal), then 8 gathers, then math.
static __device__ __forceinline__ void pull_part(const int* __restrict__ row_start,
                                                 const int2* __restrict__ sorted_cv,
                                                 int a, const _Float16* __restrict__ src,
                                                 int row, int lane, f32x4& acc)
{
    const i32x2* cv = (const i32x2*)(sorted_cv + (size_t)a * N_EDGES);
    const int* rs  = row_start + (size_t)a * (N_NODES + 1);
    const int s = rs[row], epnd = rs[row + 1];
    int e = s;
    for (; e + 7 < epnd; e += 8) {
        i32x2 p[8];
        #pragma unroll
        for (int j = 0; j < 8; ++j) p[j] = __builtin_nontemporal_load(cv + e + j);
        h4 g[8];
        #pragma unroll
        for (int j = 0; j < 8; ++j)
            g[j] = *(const h4*)(src + (size_t)p[j][0] * NHID + lane * 4);
        #pragma unroll
        for (int j = 0; j < 8; ++j) {
            const float v = __int_as_float(p[j][1]);
            acc[0] += v * (float)g[j][0];
            acc[1] += v * (float)g[j][1];
            acc[2] += v * (float)g[j][2];
            acc[3] += v * (float)g[j][3];
        }
    }
    for (; e + 3 < epnd; e += 4) {
        i32x2 p[4];
        #pragma unroll
        for (int j = 0; j < 4; ++j) p[j] = __builtin_nontemporal_load(cv + e + j);
        h4 g[4];
        #pragma unroll
        for (int j = 0; j < 4; ++j)
            g[j] = *(const h4*)(src + (size_t)p[j][0] * NHID + lane * 4);
        #pragma unroll
        for (int j = 0; j < 4; ++j) {
            const float v = __int_as_float(p[j][1]);
            acc[0] += v * (float)g[j][0];
            acc[1] += v * (float)g[j][1];
            acc[2] += v * (float)g[j][2];
            acc[3] += v * (float)g[j][3];
        }
    }
    for (; e < epnd; ++e) {
        const i32x2 p0 = __builtin_nontemporal_load(cv + e);
        const h4 g0 = *(const h4*)(src + (size_t)p0[0] * NHID + lane * 4);
        const float v0 = __int_as_float(p0[1]);
        acc[0] += v0 * (float)g0[0];
        acc[1] += v0 * (float)g0[1];
        acc[2] += v0 * (float)g0[2];
        acc[3] += v0 * (float)g0[3];
    }
}

template<int PARTS, bool LN>
__global__ __launch_bounds__(256) void pull_spmm(
    const int* __restrict__ row_start, const int2* __restrict__ sorted_cv,
    const int* __restrict__ idx_a, int pos_a, const _Float16* __restrict__ src_a,
    const int* __restrict__ idx_b, int pos_b, const _Float16* __restrict__ src_b,
    const int* __restrict__ idx_c, int pos_c, const _Float16* __restrict__ src_c,
    _Float16* __restrict__ outh, float* __restrict__ outf,
    const float* __restrict__ gamma, const float* __restrict__ beta)
{
    const int row  = (blockIdx.x * 256 + threadIdx.x) >> 6;
    const int lane = threadIdx.x & 63;
    if (row >= N_NODES) return;
    f32x4 acc = {0.f, 0.f, 0.f, 0.f};
    pull_part(row_start, sorted_cv, idx_a[pos_a], src_a, row, lane, acc);
    if constexpr (PARTS >= 2) pull_part(row_start, sorted_cv, idx_b[pos_b], src_b, row, lane, acc);
    if constexpr (PARTS >= 3) pull_part(row_start, sorted_cv, idx_c[pos_c], src_c, row, lane, acc);

    if constexpr (LN) {
        float sum = acc[0] + acc[1] + acc[2] + acc[3];
        float sq  = acc[0] * acc[0] + acc[1] * acc[1] + acc[2] * acc[2] + acc[3] * acc[3];
        #pragma unroll
        for (int off = 1; off < 64; off <<= 1) {
            sum += __shfl_xor(sum, off, 64);
            sq  += __shfl_xor(sq,  off, 64);
        }
        const float mu   = sum * (1.f / NHID);
        const float var  = sq * (1.f / NHID) - mu * mu;
        const float rstd = rsqrtf(var + LN_EPS);
        const float4 g4 = *(const float4*)(gamma + lane * 4);
        const float4 b4 = *(const float4*)(beta + lane * 4);
        const float g[4]  = {g4.x, g4.y, g4.z, g4.w};
        const float bb[4] = {b4.x, b4.y, b4.z, b4.w};
        f32x4 o;
        #pragma unroll
        for (int j = 0; j < 4; ++j) {
            const float y = (acc[j] - mu) * rstd * g[j] + bb[j];
            o[j] = 0.5f * y * (1.f + erff(y * 0.70710678118654752f));
        }
        __builtin_nontemporal_store(o, (f32x4*)(outf + (size_t)row * NHID + lane * 4));
    } else {
        h4 o;
        o[0] = (_Float16)acc[0]; o[1] = (_Float16)acc[1];
        o[2] = (_Float16)acc[2]; o[3] = (_Float16)acc[3];
        __builtin_nontemporal_store(o, (h4*)(outh + (size_t)row * NHID + lane * 4));
    }
}

extern "C" void kernel_launch(void* const* d_in, const int* in_sizes, int n_in,
                              void* d_out, int out_size, void* d_ws, size_t ws_size,
                              hipStream_t stream)
{
    (void)in_sizes; (void)n_in; (void)out_size; (void)ws_size;
    const float* x        = (const float*)d_in[0];
    const int* adj_rows   = (const int*)d_in[1];
    const int* adj_cols   = (const int*)d_in[2];
    const float* vals     = (const float*)d_in[3];
    const int* idx_seq    = (const int*)d_in[4];
    const int* idx_res    = (const int*)d_in[5];
    const float* W        = (const float*)d_in[6];
    const float* bias     = (const float*)d_in[7];
    const float* gam      = (const float*)d_in[8];
    const float* bet      = (const float*)d_in[9];

    const size_t S = (size_t)N_NODES * NHID;
    _Float16* s0 = (_Float16*)d_ws;            // 25.6 MB each
    _Float16* s1 = s0 + S;
    _Float16* s2 = s1 + S;
    int2*  sorted_cv      = (int2*)(s2 + S);                                  // 38.4 MB
    int*   row_start      = (int*)(sorted_cv + (size_t)N_ADJS * N_EDGES);     // 1.2 MB
    unsigned short* Whi   = (unsigned short*)(row_start + (size_t)N_ADJS * (N_NODES + 1)); // 128 KB
    unsigned short* Wlo   = Whi + NHID * NHID;                                // 128 KB
    int*   gcount         = (int*)(Wlo + NHID * NHID);
    int*   bstart         = gcount + N_ADJS * NB;
    int*   gcur           = bstart + N_ADJS * (NB + 1);
    // bucketed aliases s1+s2 (51.2 MB fp16 combined >= 38.4 MB needed):
    // dead once build_csr finishes, before pull1 writes s1.
    int2*  bucketed       = (int2*)s1;

    hipMemsetAsync(gcount, 0, (size_t)N_ADJS * NB * sizeof(int), stream);

    convert_w<<<dim3(NHID * NHID / 256), dim3(256), 0, stream>>>(W, Whi, Wlo);
    gemm_mfma<<<dim3((N_NODES + 63) / 64), dim3(256), 0, stream>>>(x, Whi, Wlo, bias, s0);

    const int eblocks = (N_EDGES + 4095) / 4096;
    bucket_count<<<dim3(eblocks, N_ADJS), dim3(256), 0, stream>>>(adj_rows, gcount);
    scan_buckets<<<dim3(1), dim3(384), 0, stream>>>(gcount, bstart, gcur, row_start);
    bucket_scatter<<<dim3(eblocks, N_ADJS), dim3(256), 0, stream>>>(adj_rows, adj_cols, vals, gcur, bucketed);
    build_csr<<<dim3(NB, N_ADJS), dim3(256), 0, stream>>>(bucketed, bstart, row_start, sorted_cv);

    const dim3 pgrid(N_NODES * 64 / 256);
    pull_spmm<1, false><<<pgrid, dim3(256), 0, stream>>>(row_start, sorted_cv,
        idx_seq, 0, s0,  nullptr, 0, nullptr,  nullptr, 0, nullptr,
        s1, nullptr, nullptr, nullptr);
    pull_spmm<2, false><<<pgrid, dim3(256), 0, stream>>>(row_start, sorted_cv,
        idx_seq, 1, s1,  idx_res, 0, s0,  nullptr, 0, nullptr,
        s2, nullptr, nullptr, nullptr);
    pull_spmm<3, true><<<pgrid, dim3(256), 0, stream>>>(row_start, sorted_cv,
        idx_seq, 2, s2,  idx_res, 1, s0,  idx_res, 2, s1,
        nullptr, (float*)d_out, gam, bet);
}

// Round 5
// 658.660 us; speedup vs baseline: 1.7386x; 1.1318x over previous
//
#include <hip/hip_runtime.h>
#include <math.h>

#define N_NODES 50000
#define N_EDGES 800000
#define N_ADJS  6
#define NHID    256
#define BSHIFT  7         // 128-row buckets
#define NB      391       // ceil(50000/128)
#define SLOTCAP 2560      // fixed slot capacity per bucket (mean fill ~2046, max ~2250)
#define BCAP    2816      // LDS sort capacity in build_csr
#define LN_EPS  1e-5f

typedef _Float16 f16x8 __attribute__((ext_vector_type(8)));
typedef float f32x4  __attribute__((ext_vector_type(4)));
typedef _Float16 h4  __attribute__((ext_vector_type(4)));   // 8-byte fp16 quad

// -------------------- W -> fp16 --------------------
__global__ __launch_bounds__(256) void convert_w(const float* __restrict__ W,
                                                 _Float16* __restrict__ Wh)
{
    const int i = blockIdx.x * 256 + threadIdx.x;   // 65536 total
    Wh[i] = (_Float16)W[i];
}

// -------------------- h = x @ W^T + b via MFMA (fp16 in, fp32 acc) --------------------
// Block 256 = 4 waves; block computes 64 rows x 256 cols; wave w: rows w*16..w*16+15.
__global__ __launch_bounds__(256) void gemm_mfma(const float* __restrict__ x,
                                                 const _Float16* __restrict__ Wh,
                                                 const float* __restrict__ bias,
                                                 _Float16* __restrict__ h)
{
    const int tid = threadIdx.x;
    const int w = tid >> 6, l = tid & 63;
    const int m = l & 15, q = l >> 4;
    const int row0 = blockIdx.x * 64 + w * 16;
    const int arow = row0 + m;
    const int arow_c = (arow < N_NODES) ? arow : 0;

    f32x4 acc[16];
    #pragma unroll
    for (int nt = 0; nt < 16; ++nt) acc[nt] = (f32x4){0.f, 0.f, 0.f, 0.f};

    for (int kt = 0; kt < NHID; kt += 32) {
        const float* xp = x + (size_t)arow_c * NHID + kt + q * 8;
        const float4 xa = *(const float4*)xp;
        const float4 xb = *(const float4*)(xp + 4);
        f16x8 ah;
        ah[0] = (_Float16)xa.x; ah[1] = (_Float16)xa.y;
        ah[2] = (_Float16)xa.z; ah[3] = (_Float16)xa.w;
        ah[4] = (_Float16)xb.x; ah[5] = (_Float16)xb.y;
        ah[6] = (_Float16)xb.z; ah[7] = (_Float16)xb.w;
        const int ko = kt + q * 8;
        #pragma unroll
        for (int nt = 0; nt < 16; ++nt) {
            const size_t off = (size_t)(nt * 16 + m) * NHID + ko;
            const f16x8 bh = *(const f16x8*)(Wh + off);
            acc[nt] = __builtin_amdgcn_mfma_f32_16x16x32_f16(ah, bh, acc[nt], 0, 0, 0);
        }
    }

    // C/D: col = lane&15, row = (lane>>4)*4 + reg
    #pragma unroll
    for (int nt = 0; nt < 16; ++nt) {
        const int col = nt * 16 + m;
        const float bv = bias[col];
        #pragma unroll
        for (int r = 0; r < 4; ++r) {
            const int grow = row0 + q * 4 + r;
            if (grow < N_NODES) h[(size_t)grow * NHID + col] = (_Float16)(acc[nt][r] + bv);
        }
    }
}

// -------------------- CSR build, pass A: slotted scatter (4096 edges/block) --------------------
// No prior count pass: per-block LDS aggregation reserves ranges in fixed-capacity
// slots via atomicAdd on zero-initialized gcnt. After this kernel gcnt = bucket counts.
__global__ __launch_bounds__(256) void bucket_scatter(const int* __restrict__ rows_all,
                                                      const int* __restrict__ cols_all,
                                                      const float* __restrict__ vals_all,
                                                      int* __restrict__ gcnt,
                                                      int2* __restrict__ slots)
{
    const int a = blockIdx.y;
    __shared__ int lcnt[NB], lbase[NB];
    for (int i = threadIdx.x; i < NB; i += 256) lcnt[i] = 0;
    __syncthreads();
    int bq[16], sq[16]; int2 pq[16];
    const int e0 = blockIdx.x * 4096 + threadIdx.x;
    #pragma unroll
    for (int j = 0; j < 16; ++j) {
        const int e = e0 + j * 256;
        bq[j] = -1;
        if (e < N_EDGES) {
            const size_t idx = (size_t)a * N_EDGES + e;
            const int r = rows_all[idx];
            const int b = r >> BSHIFT;
            bq[j] = b;
            sq[j] = atomicAdd(&lcnt[b], 1);
            pq[j].x = (r << 16) | cols_all[idx];
            pq[j].y = __float_as_int(vals_all[idx]);
        }
    }
    __syncthreads();
    for (int i = threadIdx.x; i < NB; i += 256)
        lbase[i] = lcnt[i] ? atomicAdd(&gcnt[a * NB + i], lcnt[i]) : 0;
    __syncthreads();
    #pragma unroll
    for (int j = 0; j < 16; ++j)
        if (bq[j] >= 0)
            slots[((size_t)a * NB + bq[j]) * SLOTCAP + lbase[bq[j]] + sq[j]] = pq[j];
}

// -------------------- CSR build: scan final counts -> compacted bstart --------------------
__global__ __launch_bounds__(384) void scan_buckets(const int* __restrict__ gcnt,
                                                    int* __restrict__ bstart,
                                                    int* __restrict__ row_start)
{
    const int lane = threadIdx.x & 63, a = threadIdx.x >> 6;
    if (a >= N_ADJS) return;
    int carry = 0;
    #pragma unroll
    for (int c = 0; c < 7; ++c) {
        const int i = c * 64 + lane;
        const int v = (i < NB) ? gcnt[a * NB + i] : 0;
        int xs = v;
        #pragma unroll
        for (int d = 1; d < 64; d <<= 1) { const int t = __shfl_up(xs, d, 64); if (lane >= d) xs += t; }
        const int excl = carry + xs - v;
        if (i < NB) bstart[a * (NB + 1) + i] = excl;
        carry += __shfl(xs, 63, 64);
    }
    if (lane == 0) {
        bstart[a * (NB + 1) + NB] = N_EDGES;
        row_start[(size_t)a * (N_NODES + 1) + N_NODES] = N_EDGES;
    }
}

// -------------------- CSR build, pass B: LDS-staged per-bucket row sort --------------------
// Reads slotted bucket, histograms, rank-scatters in LDS, writes compacted+coalesced.
__global__ __launch_bounds__(256) void build_csr(const int2* __restrict__ slots,
                                                 const int* __restrict__ bstart,
                                                 int* __restrict__ row_start,
                                                 int2* __restrict__ sorted_cv)
{
    const int a = blockIdx.y, b = blockIdx.x;
    const int s = bstart[a * (NB + 1) + b];
    const int n = bstart[a * (NB + 1) + b + 1] - s;
    __shared__ int cnt[128], cur[128];
    __shared__ int2 buf[BCAP];    // 22 KB
    __shared__ int2 buf2[BCAP];   // 22 KB
    if (threadIdx.x < 128) cnt[threadIdx.x] = 0;
    __syncthreads();
    const int2* bk = slots + ((size_t)a * NB + b) * SLOTCAP;
    const bool fits = (n <= BCAP);
    for (int i = threadIdx.x; i < n; i += 256) {
        const int2 p = bk[i];
        if (fits) buf[i] = p;
        atomicAdd(&cnt[(p.x >> 16) & 127], 1);
    }
    __syncthreads();
    const int lane = threadIdx.x & 63, wid = threadIdx.x >> 6;
    if (wid == 0) {
        const int i0 = lane * 2;
        const int c0 = cnt[i0], c1 = cnt[i0 + 1];
        const int sum = c0 + c1;
        int xs = sum;
        #pragma unroll
        for (int d = 1; d < 64; d <<= 1) { const int t = __shfl_up(xs, d, 64); if (lane >= d) xs += t; }
        const int base = xs - sum;        // exclusive, local to bucket
        const int o0 = base, o1 = base + c0;
        cur[i0] = o0; cur[i0 + 1] = o1;
        int* rs = row_start + (size_t)a * (N_NODES + 1);
        const int gr = (b << BSHIFT) + i0;
        if (gr + 0 < N_NODES) rs[gr + 0] = s + o0;
        if (gr + 1 < N_NODES) rs[gr + 1] = s + o1;
    }
    __syncthreads();
    int2* sc = sorted_cv + (size_t)a * N_EDGES;
    if (fits) {
        for (int i = threadIdx.x; i < n; i += 256) {
            const int2 p = buf[i];
            const int pos = atomicAdd(&cur[(p.x >> 16) & 127], 1);
            int2 cv; cv.x = p.x & 0xFFFF; cv.y = p.y;
            buf2[pos] = cv;
        }
        __syncthreads();
        for (int i = threadIdx.x; i < n; i += 256)
            sc[s + i] = buf2[i];                    // coalesced streaming write
    } else {
        for (int i = threadIdx.x; i < n; i += 256) {
            const int2 p = bk[i];
            const int pos = atomicAdd(&cur[(p.x >> 16) & 127], 1);
            int2 cv; cv.x = p.x & 0xFFFF; cv.y = p.y;
            sc[s + pos] = cv;
        }
    }
}

// -------------------- pull-mode SpMM over fp16 states, fp32 accumulate --------------------
static __device__ __forceinline__ void gacc(const _Float16* __restrict__ src,
                                            int col, float v, int lane, f32x4& acc)
{
    const h4 g = *(const h4*)(src + (size_t)col * NHID + lane * 4);
    acc[0] += v * (float)g[0];
    acc[1] += v * (float)g[1];
    acc[2] += v * (float)g[2];
    acc[3] += v * (float)g[3];
}

static __device__ __forceinline__ void pull_part(const int* __restrict__ row_start,
                                                 const int2* __restrict__ sorted_cv,
                                                 int a, const _Float16* __restrict__ src,
                                                 int row, int lane, f32x4& acc)
{
    const int2* cv = sorted_cv + (size_t)a * N_EDGES;
    const int* rs  = row_start + (size_t)a * (N_NODES + 1);
    const int s = rs[row], epnd = rs[row + 1];
    int e = s;
    for (; e + 3 < epnd; e += 4) {
        const int2 p0 = cv[e];
        const int2 p1 = cv[e + 1];
        const int2 p2 = cv[e + 2];
        const int2 p3 = cv[e + 3];
        gacc(src, p0.x, __int_as_float(p0.y), lane, acc);
        gacc(src, p1.x, __int_as_float(p1.y), lane, acc);
        gacc(src, p2.x, __int_as_float(p2.y), lane, acc);
        gacc(src, p3.x, __int_as_float(p3.y), lane, acc);
    }
    for (; e < epnd; ++e) {
        const int2 p0 = cv[e];
        gacc(src, p0.x, __int_as_float(p0.y), lane, acc);
    }
}

template<int PARTS, bool LN>
__global__ __launch_bounds__(256) void pull_spmm(
    const int* __restrict__ row_start, const int2* __restrict__ sorted_cv,
    const int* __restrict__ idx_a, int pos_a, const _Float16* __restrict__ src_a,
    const int* __restrict__ idx_b, int pos_b, const _Float16* __restrict__ src_b,
    const int* __restrict__ idx_c, int pos_c, const _Float16* __restrict__ src_c,
    _Float16* __restrict__ outh, float* __restrict__ outf,
    const float* __restrict__ gamma, const float* __restrict__ beta)
{
    const int row  = (blockIdx.x * 256 + threadIdx.x) >> 6;
    const int lane = threadIdx.x & 63;
    if (row >= N_NODES) return;
    f32x4 acc = {0.f, 0.f, 0.f, 0.f};
    pull_part(row_start, sorted_cv, idx_a[pos_a], src_a, row, lane, acc);
    if constexpr (PARTS >= 2) pull_part(row_start, sorted_cv, idx_b[pos_b], src_b, row, lane, acc);
    if constexpr (PARTS >= 3) pull_part(row_start, sorted_cv, idx_c[pos_c], src_c, row, lane, acc);

    if constexpr (LN) {
        float sum = acc[0] + acc[1] + acc[2] + acc[3];
        float sq  = acc[0] * acc[0] + acc[1] * acc[1] + acc[2] * acc[2] + acc[3] * acc[3];
        #pragma unroll
        for (int off = 1; off < 64; off <<= 1) {
            sum += __shfl_xor(sum, off, 64);
            sq  += __shfl_xor(sq,  off, 64);
        }
        const float mu   = sum * (1.f / NHID);
        const float var  = sq * (1.f / NHID) - mu * mu;
        const float rstd = rsqrtf(var + LN_EPS);
        const float4 g4 = *(const float4*)(gamma + lane * 4);
        const float4 b4 = *(const float4*)(beta + lane * 4);
        const float g[4]  = {g4.x, g4.y, g4.z, g4.w};
        const float bb[4] = {b4.x, b4.y, b4.z, b4.w};
        f32x4 o;
        #pragma unroll
        for (int j = 0; j < 4; ++j) {
            const float y = (acc[j] - mu) * rstd * g[j] + bb[j];
            o[j] = 0.5f * y * (1.f + erff(y * 0.70710678118654752f));
        }
        __builtin_nontemporal_store(o, (f32x4*)(outf + (size_t)row * NHID + lane * 4));
    } else {
        h4 o;
        o[0] = (_Float16)acc[0]; o[1] = (_Float16)acc[1];
        o[2] = (_Float16)acc[2]; o[3] = (_Float16)acc[3];
        __builtin_nontemporal_store(o, (h4*)(outh + (size_t)row * NHID + lane * 4));
    }
}

extern "C" void kernel_launch(void* const* d_in, const int* in_sizes, int n_in,
                              void* d_out, int out_size, void* d_ws, size_t ws_size,
                              hipStream_t stream)
{
    (void)in_sizes; (void)n_in; (void)out_size; (void)ws_size;
    const float* x        = (const float*)d_in[0];
    const int* adj_rows   = (const int*)d_in[1];
    const int* adj_cols   = (const int*)d_in[2];
    const float* vals     = (const float*)d_in[3];
    const int* idx_seq    = (const int*)d_in[4];
    const int* idx_res    = (const int*)d_in[5];
    const float* W        = (const float*)d_in[6];
    const float* bias     = (const float*)d_in[7];
    const float* gam      = (const float*)d_in[8];
    const float* bet      = (const float*)d_in[9];

    const size_t S = (size_t)N_NODES * NHID;
    _Float16* s0 = (_Float16*)d_ws;            // 25.6 MB each
    _Float16* s1 = s0 + S;
    _Float16* s2 = s1 + S;
    int2*  sorted_cv      = (int2*)(s2 + S);                                  // 38.4 MB
    int*   row_start      = (int*)(sorted_cv + (size_t)N_ADJS * N_EDGES);     // 1.2 MB
    _Float16* Wh          = (_Float16*)(row_start + (size_t)N_ADJS * (N_NODES + 1)); // 128 KB
    int*   gcnt           = (int*)(Wh + NHID * NHID);
    int*   bstart         = gcnt + N_ADJS * NB;
    // slots alias s1+s2: 6*391*2560*8 = 48.0 MB <= 51.2 MB; dead before pull1 writes s1.
    int2*  slots          = (int2*)s1;

    hipMemsetAsync(gcnt, 0, (size_t)N_ADJS * NB * sizeof(int), stream);

    convert_w<<<dim3(NHID * NHID / 256), dim3(256), 0, stream>>>(W, Wh);
    gemm_mfma<<<dim3((N_NODES + 63) / 64), dim3(256), 0, stream>>>(x, Wh, bias, s0);

    const int eblocks = (N_EDGES + 4095) / 4096;
    bucket_scatter<<<dim3(eblocks, N_ADJS), dim3(256), 0, stream>>>(adj_rows, adj_cols, vals, gcnt, slots);
    scan_buckets<<<dim3(1), dim3(384), 0, stream>>>(gcnt, bstart, row_start);
    build_csr<<<dim3(NB, N_ADJS), dim3(256), 0, stream>>>(slots, bstart, row_start, sorted_cv);

    const dim3 pgrid(N_NODES * 64 / 256);
    pull_spmm<1, false><<<pgrid, dim3(256), 0, stream>>>(row_start, sorted_cv,
        idx_seq, 0, s0,  nullptr, 0, nullptr,  nullptr, 0, nullptr,
        s1, nullptr, nullptr, nullptr);
    pull_spmm<2, false><<<pgrid, dim3(256), 0, stream>>>(row_start, sorted_cv,
        idx_seq, 1, s1,  idx_res, 0, s0,  nullptr, 0, nullptr,
        s2, nullptr, nullptr, nullptr);
    pull_spmm<3, true><<<pgrid, dim3(256), 0, stream>>>(row_start, sorted_cv,
        idx_seq, 2, s2,  idx_res, 1, s0,  idx_res, 2, s1,
        nullptr, (float*)d_out, gam, bet);
}